// Round 1
// baseline (3186.528 us; speedup 1.0000x reference)
//
#include <hip/hip_runtime.h>
#include <hip/hip_cooperative_groups.h>

namespace cg = cooperative_groups;

#define NB 2048            // real cost-matrix dim
#define NF 4096            // padded dim
#define GRID_BLOCKS 256    // 1 block per CU
#define BLOCK_THREADS 512  // 8 waves per block -> 2048 waves total (one per row)

// fp64 exp, |rel err| ~3e-13 on our range (args in ~[-120, +40]).
// Range-reduce by ln2, degree-10 Taylor, scale via exponent bits.
static __device__ __forceinline__ double fexp(double x) {
  x = fmax(x, -700.0);
  double t = x * 1.4426950408889634074;          // log2(e)
  double n = rint(t);
  double r = fma(n, -0.69314718055994530942, x); // |r| <= ln2/2
  double p = 2.7557319223985890653e-7;           // 1/10!
  p = fma(p, r, 2.7557319223985890653e-6);       // 1/9!
  p = fma(p, r, 2.4801587301587301587e-5);       // 1/8!
  p = fma(p, r, 1.9841269841269841270e-4);       // 1/7!
  p = fma(p, r, 1.3888888888888888889e-3);       // 1/6!
  p = fma(p, r, 8.3333333333333333333e-3);       // 1/5!
  p = fma(p, r, 4.1666666666666666667e-2);       // 1/4!
  p = fma(p, r, 1.6666666666666666667e-1);       // 1/3!
  p = fma(p, r, 0.5);
  p = fma(p, r, 1.0);
  p = fma(p, r, 1.0);
  long long bits = ((long long)(1023 + (int)n)) << 52;
  return p * __longlong_as_double(bits);
}

// One Sinkhorn half-step (row update on Mat; column update == row update on Mat^T).
// State is stored pre-divided by eps:  vin[j] = v_j/eps,  vout[i] = u_i/eps.
//   vout[w]   = logp - log( sum_j exp(vin[j] - 20*Mat[w][j]) + 2048*exp(vinpad) )
//   voutpad   = logp - log( sum_j exp(vin[j])                + 2048*exp(vinpad) )
// where sum_j exp(vin[j]) comes from partPrev (per-block partials of the
// previous phase: e^{vout/eps} = (1/4096)/R, no extra exps, no atomics).
__device__ __forceinline__ void half_step(const float* __restrict__ Mat,
                                          const double* __restrict__ vin,
                                          const double* __restrict__ vinpad,
                                          double* __restrict__ vout,
                                          double* __restrict__ voutpad,
                                          const double* __restrict__ partPrev,
                                          double* __restrict__ partOut,
                                          double* s_part,
                                          const cg::grid_group& g) {
  const double LOGP = -8.3177661667193437130;  // -log(4096), fp64
  int gtid = blockIdx.x * BLOCK_THREADS + threadIdx.x;
  int w = gtid >> 6;          // 0..2047 : one wave per row
  int lane = gtid & 63;
  double vpad = *vinpad;
  double P = 2048.0 * fexp(vpad);  // pad-column (resp. pad-row) contribution

  // Wave 0: compute the shared pad-row/col dual value for the NEXT phase's readers.
  if (w == 0) {
    double s = partPrev[lane] + partPrev[lane + 64] +
               partPrev[lane + 128] + partPrev[lane + 192];
#pragma unroll
    for (int off = 32; off > 0; off >>= 1) s += __shfl_xor(s, off, 64);
    if (lane == 0) *voutpad = LOGP - log(s + P);
  }

  const float* row = Mat + (size_t)w * NB;
  double a0 = 0.0, a1 = 0.0, a2 = 0.0, a3 = 0.0;  // 4 independent exp chains (ILP)
  int base = lane * 4;
#pragma unroll
  for (int k = 0; k < 8; ++k) {
    float4 c = *reinterpret_cast<const float4*>(row + base + 256 * k);
    double2 vA = *reinterpret_cast<const double2*>(vin + base + 256 * k);
    double2 vB = *reinterpret_cast<const double2*>(vin + base + 256 * k + 2);
    a0 += fexp(fma(-20.0, (double)c.x, vA.x));
    a1 += fexp(fma(-20.0, (double)c.y, vA.y));
    a2 += fexp(fma(-20.0, (double)c.z, vB.x));
    a3 += fexp(fma(-20.0, (double)c.w, vB.y));
  }
  double acc = (a0 + a1) + (a2 + a3);
#pragma unroll
  for (int off = 32; off > 0; off >>= 1) acc += __shfl_xor(acc, off, 64);

  if (lane == 0) {
    double R = acc + P;
    vout[w] = LOGP - log(R);
    s_part[threadIdx.x >> 6] = 2.44140625e-4 / R;  // e^{vout[w]} = (1/4096)/R
  }
  __syncthreads();
  if (threadIdx.x == 0) {
    double ps = 0.0;
#pragma unroll
    for (int q = 0; q < 8; ++q) ps += s_part[q];
    partOut[blockIdx.x] = ps;
  }
  g.sync();
}

__global__ __launch_bounds__(BLOCK_THREADS, 2) void sinkhorn_kernel(
    const float* __restrict__ C, float* __restrict__ out) {
  cg::grid_group grid = cg::this_grid();
  __shared__ float s_tile[64][65];
  __shared__ double s_vs[2049];
  __shared__ double s_us[16];
  __shared__ float s_cst[16];
  __shared__ double s_part[8];

  // Scratch lives inside d_out; final output pass overwrites all of it.
  float* CT = out;                                         // 2048*2048 floats
  double* uv = reinterpret_cast<double*>(out + (size_t)NB * NB);
  double* us = uv;           // u/eps, 2048
  double* vs = uv + 2048;    // v/eps, 2048
  double* us_pad = uv + 4096;
  double* vs_pad = uv + 4097;
  double* pU = uv + 4104;    // per-block partials of sum_i e^{us_i}, 256
  double* pV = uv + 4360;    // per-block partials of sum_j e^{vs_j}, 256

  // ---- init (d_out is poisoned every launch; re-init everything) ----
  if (blockIdx.x == 0) {
    for (int i = threadIdx.x; i < 2048; i += BLOCK_THREADS) vs[i] = 0.0;
    if (threadIdx.x < GRID_BLOCKS)
      pV[threadIdx.x] = (threadIdx.x == 0) ? 2048.0 : 0.0;  // sum e^0 over 2048 cols
    if (threadIdx.x == 0) *vs_pad = 0.0;
  }
  // ---- transpose C -> CT for coalesced column sweeps ----
  for (int tile = blockIdx.x; tile < 1024; tile += GRID_BLOCKS) {
    int ti = tile >> 5, tj = tile & 31;
    int r = threadIdx.x >> 6, cc = threadIdx.x & 63;
#pragma unroll
    for (int k = 0; k < 8; ++k)
      s_tile[r + 8 * k][cc] = C[(size_t)(ti * 64 + r + 8 * k) * NB + (tj * 64 + cc)];
    __syncthreads();
#pragma unroll
    for (int k = 0; k < 8; ++k)
      CT[(size_t)(tj * 64 + r + 8 * k) * NB + (ti * 64 + cc)] = s_tile[cc][r + 8 * k];
    __syncthreads();
  }
  grid.sync();

  // ---- 50 Sinkhorn steps (row update, then column update) ----
  for (int t = 0; t < 50; ++t) {
    half_step(C,  vs, vs_pad, us, us_pad, pV, pU, s_part, grid);
    half_step(CT, us, us_pad, vs, vs_pad, pU, pV, s_part, grid);
  }

  // ---- stage duals to LDS, then overwrite d_out with the transport plan ----
  for (int i = threadIdx.x; i < 2048; i += BLOCK_THREADS) s_vs[i] = vs[i];
  if (threadIdx.x == 0) s_vs[2048] = *vs_pad;
  if (threadIdx.x < 16) {
    int i = blockIdx.x * 16 + threadIdx.x;
    s_us[threadIdx.x] = (i < 2048) ? us[i] : *us_pad;
  }
  __syncthreads();
  grid.sync();  // all blocks staged -> safe to clobber scratch region

  if (threadIdx.x < 16) {
    double lp = s_us[threadIdx.x] + s_vs[2048];  // right half: C=0, v=v_pad
    s_cst[threadIdx.x] = (float)(4096.0 * fexp(fmin(lp, 0.0)));
  }
  __syncthreads();
  int r0 = blockIdx.x * 16;  // 16 output rows per block
  for (int e = threadIdx.x; e < 16 * 4096; e += BLOCK_THREADS) {
    int il = e >> 12;
    int j = e & 4095;
    int i = r0 + il;
    float val;
    if (j < 2048) {
      double lp = s_us[il] + s_vs[j];
      if (i < 2048) lp = fma(-20.0, (double)C[(size_t)i * NB + j], lp);
      val = (float)(4096.0 * fexp(fmin(lp, 0.0)));
    } else {
      val = s_cst[il];
    }
    out[(size_t)i * NF + j] = val;
  }
}

extern "C" void kernel_launch(void* const* d_in, const int* in_sizes, int n_in,
                              void* d_out, int out_size, void* d_ws, size_t ws_size,
                              hipStream_t stream) {
  (void)in_sizes; (void)n_in; (void)d_ws; (void)ws_size; (void)out_size;
  const float* C = (const float*)d_in[0];
  float* out = (float*)d_out;
  void* args[] = {(void*)&C, (void*)&out};
  hipLaunchCooperativeKernel((void*)sinkhorn_kernel, dim3(GRID_BLOCKS),
                             dim3(BLOCK_THREADS), args, 0, stream);
}

// Round 2
// 702.964 us; speedup vs baseline: 4.5330x; 4.5330x over previous
//
#include <hip/hip_runtime.h>

// Sinkhorn in z-space: z_j = e^{v_j/eps}, w_i = e^{u_i/eps}. Since u cancels in
// its own update, each step is pure fp64 arithmetic on K = exp(-20*C):
//   row:  R_i = sum_j K_ij z_j + 2048*zpad ;  w_i = (1/4096)/R_i
//   col:  c_j = sum_i K_ij w_i + 2048*wpad ;  z_j = (1/4096)/c_j
//   pads: wpad = (1/4096)/(sum_j z_j + 2048*zpad); zpad = (1/4096)/(sum_i w_i + 2048*wpad)
// Output: out_ij = 4096*min(w_i z_j K_ij, 1).  No exp/log in the loop at all.
//
// Multi-kernel graph (103 dispatches) instead of cooperative grid.sync():
// kernel boundaries provide cross-XCD visibility at ~2us instead of ~30us.

#define INV_N (1.0 / 4096.0)

// ---- scratch layout inside d_out (67,108,864 bytes) ----
#define OFF_K 0UL            // K: 2048x2048 fp64 = bytes [0, 33554432) = out rows 0..2047
#define OFF_CB 33554432UL    // col partials: 256 x 2048 fp64 (out rows 2048..2303, dead at epilogue)
#define OFF_SWB 37748736UL   // 256 fp64 per-block sums of w
#define OFF_SZB 37750784UL   // 32 fp64 per-block sums of z
#define OFF_W 67059712UL     // w: 2048 fp64 = out row 4093
#define OFF_Z 67076096UL     // z: 2048 fp64 = out row 4094
#define OFF_SCAL 67092480UL  // scal[0]=wpad scal[1]=zpad = out row 4095 head

// fp64 exp (rel err ~3e-13 on [-20,0]) for the one-time K build.
static __device__ __forceinline__ double fexp(double x) {
  double t = x * 1.4426950408889634074;
  double n = rint(t);
  double r = fma(n, -0.69314718055994530942, x);
  double p = 2.7557319223985890653e-7;
  p = fma(p, r, 2.7557319223985890653e-6);
  p = fma(p, r, 2.4801587301587301587e-5);
  p = fma(p, r, 1.9841269841269841270e-4);
  p = fma(p, r, 1.3888888888888888889e-3);
  p = fma(p, r, 8.3333333333333333333e-3);
  p = fma(p, r, 4.1666666666666666667e-2);
  p = fma(p, r, 1.6666666666666666667e-1);
  p = fma(p, r, 0.5);
  p = fma(p, r, 1.0);
  p = fma(p, r, 1.0);
  long long bits = ((long long)(1023 + (int)n)) << 52;
  return p * __longlong_as_double(bits);
}

// K = exp(-20 C), plus state init. 2048 blocks x 512 thr, 4 elems/thread.
__global__ __launch_bounds__(512) void k_build(const float* __restrict__ C, char* base) {
  double* K = (double*)(base + OFF_K);
  size_t idx = ((size_t)blockIdx.x * 512 + threadIdx.x) * 4;
  float4 c = *(const float4*)(C + idx);
  double2 d0, d1;
  d0.x = fexp(-20.0 * (double)c.x);
  d0.y = fexp(-20.0 * (double)c.y);
  d1.x = fexp(-20.0 * (double)c.z);
  d1.y = fexp(-20.0 * (double)c.w);
  ((double2*)(K + idx))[0] = d0;
  ((double2*)(K + idx))[1] = d1;
  if (blockIdx.x == 0) {
    double* z = (double*)(base + OFF_Z);
    double* scal = (double*)(base + OFF_SCAL);
    double* SzB = (double*)(base + OFF_SZB);
    for (int t = threadIdx.x; t < 2048; t += 512) z[t] = 1.0;
    if (threadIdx.x < 32) SzB[threadIdx.x] = (threadIdx.x == 0) ? 2048.0 : 0.0;
    if (threadIdx.x == 0) scal[1] = 1.0;  // zpad
  }
}

// Row update + column partials. 256 blocks x 512 thr; wave per row (8 rows/block).
__global__ __launch_bounds__(512) void k_rows(char* base) {
  const double* K = (const double*)(base + OFF_K);
  double* cB = (double*)(base + OFF_CB);
  double* SwB = (double*)(base + OFF_SWB);
  const double* SzB = (const double*)(base + OFF_SZB);
  double* w = (double*)(base + OFF_W);
  const double* z = (const double*)(base + OFF_Z);
  double* scal = (double*)(base + OFF_SCAL);
  __shared__ double s_z[2048];
  __shared__ double s_w[8];
  __shared__ double s_zpad;
  int tid = threadIdx.x, b = blockIdx.x;
  for (int t = tid; t < 1024; t += 512) ((double2*)s_z)[t] = ((const double2*)z)[t];
  if (tid == 0) s_zpad = scal[1];
  __syncthreads();
  int wv = tid >> 6, l = tid & 63;
  int i = b * 8 + wv;
  const double2* Kr = (const double2*)(K + (size_t)i * 2048);
  const double2* zr = (const double2*)s_z;
  double a0 = 0, a1 = 0, a2 = 0, a3 = 0;
#pragma unroll
  for (int k = 0; k < 16; k += 2) {
    double2 k0 = Kr[l + 64 * k], k1 = Kr[l + 64 * (k + 1)];
    double2 z0 = zr[l + 64 * k], z1 = zr[l + 64 * (k + 1)];
    a0 = fma(k0.x, z0.x, a0);
    a1 = fma(k0.y, z0.y, a1);
    a2 = fma(k1.x, z1.x, a2);
    a3 = fma(k1.y, z1.y, a3);
  }
  double acc = (a0 + a1) + (a2 + a3);
#pragma unroll
  for (int off = 32; off; off >>= 1) acc += __shfl_xor(acc, off, 64);
  double wi = INV_N / (acc + 2048.0 * s_zpad);
  if (l == 0) {
    w[i] = wi;
    s_w[wv] = wi;
  }
  __syncthreads();
  if (tid == 0) {
    double s = 0;
#pragma unroll
    for (int q = 0; q < 8; ++q) s += s_w[q];
    SwB[b] = s;
  }
  if (b == 0 && wv == 0) {  // pad-row dual for this step
    double t = (l < 32) ? SzB[l] : 0.0;
#pragma unroll
    for (int off = 32; off; off >>= 1) t += __shfl_xor(t, off, 64);
    if (l == 0) scal[0] = INV_N / (t + 2048.0 * s_zpad);
  }
  // pass 2: column partials from this block's 8 rows (K re-read hits L1/L2)
  int j0 = wv * 256 + l * 4;
  const double* Kb = K + (size_t)(b * 8) * 2048;
  double c0 = 0, c1 = 0, c2 = 0, c3 = 0;
#pragma unroll
  for (int r = 0; r < 8; ++r) {
    double wr = s_w[r];
    const double2* p = (const double2*)(Kb + (size_t)r * 2048 + j0);
    double2 p0 = p[0], p1 = p[1];
    c0 = fma(p0.x, wr, c0);
    c1 = fma(p0.y, wr, c1);
    c2 = fma(p1.x, wr, c2);
    c3 = fma(p1.y, wr, c3);
  }
  double2* dst = (double2*)(cB + (size_t)b * 2048 + j0);
  double2 o0, o1;
  o0.x = c0; o0.y = c1; o1.x = c2; o1.y = c3;
  dst[0] = o0;
  dst[1] = o1;
}

// Column reduce -> z. 32 blocks x 512 thr; block owns 64 columns.
__global__ __launch_bounds__(512) void k_cols(char* base) {
  const double* cB = (const double*)(base + OFF_CB);
  const double* SwB = (const double*)(base + OFF_SWB);
  double* SzB = (double*)(base + OFF_SZB);
  double* z = (double*)(base + OFF_Z);
  double* scal = (double*)(base + OFF_SCAL);
  __shared__ double s_part[512];
  int tid = threadIdx.x, bb = blockIdx.x;
  int wv = tid >> 6, l = tid & 63;
  double wpad = scal[0];
  int j = bb * 64 + l;
  const double* src = cB + (size_t)(wv * 32) * 2048 + j;
  double a0 = 0, a1 = 0, a2 = 0, a3 = 0;
#pragma unroll
  for (int t = 0; t < 32; t += 4) {
    a0 += src[(size_t)t * 2048];
    a1 += src[(size_t)(t + 1) * 2048];
    a2 += src[(size_t)(t + 2) * 2048];
    a3 += src[(size_t)(t + 3) * 2048];
  }
  s_part[tid] = (a0 + a1) + (a2 + a3);
  __syncthreads();
  if (wv == 0) {
    double c = 2048.0 * wpad;
#pragma unroll
    for (int q = 0; q < 8; ++q) c += s_part[q * 64 + l];
    double zj = INV_N / c;
    z[j] = zj;
    double s = zj;
#pragma unroll
    for (int off = 32; off; off >>= 1) s += __shfl_xor(s, off, 64);
    if (l == 0) SzB[bb] = s;
  }
  if (bb == 0 && wv == 7) {  // pad-col dual for this step
    double t = SwB[l] + SwB[l + 64] + SwB[l + 128] + SwB[l + 192];
#pragma unroll
    for (int off = 32; off; off >>= 1) t += __shfl_xor(t, off, 64);
    if (l == 0) scal[1] = INV_N / (t + 2048.0 * wpad);
  }
}

// Output rows 0..2047 (in-place over K, 2-row LDS staging). 256 blocks x 512.
__global__ __launch_bounds__(512) void k_out_top(char* base) {
  const double* K = (const double*)(base + OFF_K);
  const double* w = (const double*)(base + OFF_W);
  const double* z = (const double*)(base + OFF_Z);
  const double* scal = (const double*)(base + OFF_SCAL);
  float* out = (float*)base;
  __shared__ double s_z[2048];
  __shared__ double s_K[4096];
  __shared__ double s_wr[8];
  int tid = threadIdx.x, b = blockIdx.x;
  for (int t = tid; t < 1024; t += 512) ((double2*)s_z)[t] = ((const double2*)z)[t];
  if (tid < 8) s_wr[tid] = w[b * 8 + tid];
  double zpad = scal[1];
#pragma unroll 1
  for (int c = 0; c < 4; ++c) {
    int r0 = b * 8 + 2 * c;
    __syncthreads();  // also guards s_z/s_wr staging (c==0) and s_K reuse (c>0)
    const double2* src = (const double2*)(K + (size_t)r0 * 2048);
    for (int t = tid; t < 2048; t += 512) ((double2*)s_K)[t] = src[t];
    __syncthreads();
    int rs = tid >> 8, tt = tid & 255;
    int i = r0 + rs;
    double wi = s_wr[2 * c + rs];
    int j = tt * 8;
    const double* kp = s_K + rs * 2048 + j;
    const double* zp = s_z + j;
    float4 f0, f1;
    f0.x = (float)(4096.0 * fmin(wi * zp[0] * kp[0], 1.0));
    f0.y = (float)(4096.0 * fmin(wi * zp[1] * kp[1], 1.0));
    f0.z = (float)(4096.0 * fmin(wi * zp[2] * kp[2], 1.0));
    f0.w = (float)(4096.0 * fmin(wi * zp[3] * kp[3], 1.0));
    f1.x = (float)(4096.0 * fmin(wi * zp[4] * kp[4], 1.0));
    f1.y = (float)(4096.0 * fmin(wi * zp[5] * kp[5], 1.0));
    f1.z = (float)(4096.0 * fmin(wi * zp[6] * kp[6], 1.0));
    f1.w = (float)(4096.0 * fmin(wi * zp[7] * kp[7], 1.0));
    float* orow = out + (size_t)i * 4096;
    ((float4*)(orow + j))[0] = f0;
    ((float4*)(orow + j))[1] = f1;
    float cr = (float)(4096.0 * fmin(wi * zpad, 1.0));
    float4 fc;
    fc.x = cr; fc.y = cr; fc.z = cr; fc.w = cr;
    ((float4*)(orow + 2048 + j))[0] = fc;
    ((float4*)(orow + 2048 + j))[1] = fc;
  }
}

// Output rows 2048..4092 (identical rows; avoids tail stash). 256 blocks x 512.
__global__ __launch_bounds__(512) void k_out_bot(char* base) {
  const double* z = (const double*)(base + OFF_Z);
  const double* scal = (const double*)(base + OFF_SCAL);
  float* out = (float*)base;
  __shared__ float s_val[2048];
  int tid = threadIdx.x, b = blockIdx.x;
  double wpad = scal[0], zpad = scal[1];
  {
    int j = tid * 4;
    double2 z0 = ((const double2*)(z + j))[0];
    double2 z1 = ((const double2*)(z + j))[1];
    s_val[j + 0] = (float)(4096.0 * fmin(wpad * z0.x, 1.0));
    s_val[j + 1] = (float)(4096.0 * fmin(wpad * z0.y, 1.0));
    s_val[j + 2] = (float)(4096.0 * fmin(wpad * z1.x, 1.0));
    s_val[j + 3] = (float)(4096.0 * fmin(wpad * z1.y, 1.0));
  }
  float cf = (float)(4096.0 * fmin(wpad * zpad, 1.0));
  __syncthreads();
  int wv = tid >> 6, l = tid & 63;
  int row = 2048 + b * 8 + wv;
  if (row <= 4092) {
    float4* orow = (float4*)(out + (size_t)row * 4096);
    float4 fc;
    fc.x = cf; fc.y = cf; fc.z = cf; fc.w = cf;
#pragma unroll
    for (int k = 0; k < 8; ++k) orow[l + 64 * k] = ((const float4*)s_val)[l + 64 * k];
#pragma unroll
    for (int k = 0; k < 8; ++k) orow[512 + l + 64 * k] = fc;
  }
}

// Output rows 4093..4095 (overwrites the w/z/scal stash; single block = ordered).
__global__ __launch_bounds__(512) void k_out_tail(char* base) {
  const double* z = (const double*)(base + OFF_Z);
  const double* scal = (const double*)(base + OFF_SCAL);
  float* out = (float*)base;
  __shared__ float s_val[2048];
  int tid = threadIdx.x;
  double wpad = scal[0], zpad = scal[1];
  {
    int j = tid * 4;
    double2 z0 = ((const double2*)(z + j))[0];
    double2 z1 = ((const double2*)(z + j))[1];
    s_val[j + 0] = (float)(4096.0 * fmin(wpad * z0.x, 1.0));
    s_val[j + 1] = (float)(4096.0 * fmin(wpad * z0.y, 1.0));
    s_val[j + 2] = (float)(4096.0 * fmin(wpad * z1.x, 1.0));
    s_val[j + 3] = (float)(4096.0 * fmin(wpad * z1.y, 1.0));
  }
  float cf = (float)(4096.0 * fmin(wpad * zpad, 1.0));
  __syncthreads();  // all reads of z/scal done before any write below
  float4 fc;
  fc.x = cf; fc.y = cf; fc.z = cf; fc.w = cf;
  for (int row = 4093; row <= 4095; ++row) {
    float4* orow = (float4*)(out + (size_t)row * 4096);
    for (int t = tid; t < 1024; t += 512)
      orow[t] = (t < 512) ? ((const float4*)s_val)[t] : fc;
  }
}

extern "C" void kernel_launch(void* const* d_in, const int* in_sizes, int n_in,
                              void* d_out, int out_size, void* d_ws, size_t ws_size,
                              hipStream_t stream) {
  (void)in_sizes; (void)n_in; (void)d_ws; (void)ws_size; (void)out_size;
  const float* C = (const float*)d_in[0];
  char* base = (char*)d_out;
  k_build<<<2048, 512, 0, stream>>>(C, base);
  for (int t = 0; t < 50; ++t) {
    k_rows<<<256, 512, 0, stream>>>(base);
    k_cols<<<32, 512, 0, stream>>>(base);
  }
  k_out_top<<<256, 512, 0, stream>>>(base);
  k_out_bot<<<256, 512, 0, stream>>>(base);
  k_out_tail<<<1, 512, 0, stream>>>(base);
}

// Round 3
// 461.907 us; speedup vs baseline: 6.8986x; 1.5219x over previous
//
#include <hip/hip_runtime.h>

// Sinkhorn in z-space, fp32 kernel matrix + fp64 state.
//   z_j = e^{v_j/eps}, w_i = e^{u_i/eps}, K = exp(-20*C) stored fp32 (and K^T).
//   row:  w_i = (1/4096) / (sum_j K_ij z_j + 2048*zpad)
//   col:  z_j = (1/4096) / (sum_i K^T_ji w_i + 2048*wpad)
//   pads: wpad = (1/4096)/(sum_j z_j + 2048*zpad);  zpad symmetric.
// Epilogue recomputes exp(-20C) in fp64 from C so fp32-K error only enters
// through the duals (expected ~1e-8 rel after row-sum cancellation).
// 104 dispatches; per-XCD working set 4 MB -> L2-resident loop.

#define INV_N (1.0 / 4096.0)

// ---- scratch layout inside d_out (67,108,864 bytes) ----
#define OFF_K 0UL             // K  fp32 2048x2048 = [0, 16777216)
#define OFF_KT 16777216UL     // KT fp32 2048x2048 = [16777216, 33554432) -> out rows 0..2047
#define OFF_W 67059712UL      // w: 2048 fp64 = out row 4093
#define OFF_Z 67076096UL      // z: 2048 fp64 = out row 4094
#define OFF_SCAL 67092480UL   // scal[0]=wpad scal[1]=zpad   (out row 4095)
#define OFF_SWB 67092544UL    // 256 fp64 per-block sums of w
#define OFF_SZB 67094592UL    // 256 fp64 per-block sums of z

// fp64 exp (rel err ~3e-13 on [-20,0]).
static __device__ __forceinline__ double fexp(double x) {
  double t = x * 1.4426950408889634074;
  double n = rint(t);
  double r = fma(n, -0.69314718055994530942, x);
  double p = 2.7557319223985890653e-7;
  p = fma(p, r, 2.7557319223985890653e-6);
  p = fma(p, r, 2.4801587301587301587e-5);
  p = fma(p, r, 1.9841269841269841270e-4);
  p = fma(p, r, 1.3888888888888888889e-3);
  p = fma(p, r, 8.3333333333333333333e-3);
  p = fma(p, r, 4.1666666666666666667e-2);
  p = fma(p, r, 1.6666666666666666667e-1);
  p = fma(p, r, 0.5);
  p = fma(p, r, 1.0);
  p = fma(p, r, 1.0);
  long long bits = ((long long)(1023 + (int)n)) << 52;
  return p * __longlong_as_double(bits);
}

// Build K (fp32) + KT (fp32, via LDS tile transpose) + init state.
// 1024 blocks x 256 thr; one 64x64 tile per block.
__global__ __launch_bounds__(256) void k_build(const float* __restrict__ C, char* base) {
  float* K = (float*)(base + OFF_K);
  float* KT = (float*)(base + OFF_KT);
  __shared__ float s_t[64][65];
  int b = blockIdx.x, tid = threadIdx.x;
  int ti = b >> 5, tj = b & 31;
  int r0 = tid >> 6, c = tid & 63;
#pragma unroll
  for (int k = 0; k < 16; ++k) {
    int r = r0 + 4 * k;
    int row = ti * 64 + r, col = tj * 64 + c;
    float f = (float)fexp(-20.0 * (double)C[(size_t)row * 2048 + col]);
    K[(size_t)row * 2048 + col] = f;
    s_t[r][c] = f;
  }
  __syncthreads();
#pragma unroll
  for (int k = 0; k < 16; ++k) {
    int r = r0 + 4 * k;
    KT[(size_t)(tj * 64 + r) * 2048 + ti * 64 + c] = s_t[c][r];
  }
  if (b == 0) {
    double* z = (double*)(base + OFF_Z);
    double* scal = (double*)(base + OFF_SCAL);
    double* SzB = (double*)(base + OFF_SZB);
    for (int t = tid; t < 2048; t += 256) z[t] = 1.0;
    SzB[tid] = (tid == 0) ? 2048.0 : 0.0;
    if (tid == 0) scal[1] = 1.0;  // zpad
  }
}

// One half-step: vout_i = INV_N/(sum_j M_ij vin_j + 2048*padIn).
// Also: designated wave computes padOut = INV_N/(sum(vin) + 2048*padIn)
// from SpIn partials; every block writes SpOut[b] = local sum of vout.
// 256 blocks x 512 thr; wave per row (8 rows/block).
__global__ __launch_bounds__(512) void k_half(const float* __restrict__ M,
                                              const double* __restrict__ vin,
                                              double* __restrict__ vout,
                                              const double* __restrict__ SpIn,
                                              double* __restrict__ SpOut,
                                              const double* __restrict__ padIn,
                                              double* __restrict__ padOut) {
  __shared__ double s_z[2048];
  __shared__ double s_w[8];
  int tid = threadIdx.x, b = blockIdx.x;
  const double2* zg = (const double2*)vin;
  ((double2*)s_z)[tid] = zg[tid];
  ((double2*)s_z)[tid + 512] = zg[tid + 512];
  double pads = *padIn;
  __syncthreads();
  int wv = tid >> 6, l = tid & 63;
  int i = b * 8 + wv;
  const float4* Mr = (const float4*)(M + (size_t)i * 2048);
  const double2* zr = (const double2*)s_z;
  double a0 = 0, a1 = 0, a2 = 0, a3 = 0;
#pragma unroll
  for (int k = 0; k < 8; ++k) {
    float4 m = Mr[l + 64 * k];
    double2 z0 = zr[2 * (l + 64 * k)];
    double2 z1 = zr[2 * (l + 64 * k) + 1];
    a0 = fma((double)m.x, z0.x, a0);
    a1 = fma((double)m.y, z0.y, a1);
    a2 = fma((double)m.z, z1.x, a2);
    a3 = fma((double)m.w, z1.y, a3);
  }
  double acc = (a0 + a1) + (a2 + a3);
#pragma unroll
  for (int off = 32; off; off >>= 1) acc += __shfl_xor(acc, off, 64);
  double wi = INV_N / (acc + 2048.0 * pads);
  if (l == 0) {
    vout[i] = wi;
    s_w[wv] = wi;
  }
  __syncthreads();
  if (tid == 0) {
    double s = 0;
#pragma unroll
    for (int q = 0; q < 8; ++q) s += s_w[q];
    SpOut[b] = s;
  }
  if (b == 0 && wv == 7) {  // pad dual for the NEXT half-step
    double t = SpIn[l] + SpIn[l + 64] + SpIn[l + 128] + SpIn[l + 192];
#pragma unroll
    for (int off = 32; off; off >>= 1) t += __shfl_xor(t, off, 64);
    if (l == 0) *padOut = INV_N / (t + 2048.0 * pads);
  }
}

// Output rows 0..2047: out_ij = 4096*min(w_i z_j exp(-20 C_ij), 1), fp64 exp.
// Right half (j>=2048): 4096*min(w_i*zpad, 1). 256 blocks x 512 thr.
__global__ __launch_bounds__(512) void k_out_top(const float* __restrict__ C, char* base) {
  const double* w = (const double*)(base + OFF_W);
  const double* z = (const double*)(base + OFF_Z);
  const double* scal = (const double*)(base + OFF_SCAL);
  float* out = (float*)base;
  __shared__ double s_z[2048];
  __shared__ double s_w[8];
  int tid = threadIdx.x, b = blockIdx.x;
  const double2* zg = (const double2*)z;
  ((double2*)s_z)[tid] = zg[tid];
  ((double2*)s_z)[tid + 512] = zg[tid + 512];
  if (tid < 8) s_w[tid] = w[b * 8 + tid];
  double zpad = scal[1];
  __syncthreads();
  int wv = tid >> 6, l = tid & 63;
  int i = b * 8 + wv;
  double wi = s_w[wv];
  const float4* Cr = (const float4*)(C + (size_t)i * 2048);
  const double2* zr = (const double2*)s_z;
  float* orow = out + (size_t)i * 4096;
#pragma unroll 2
  for (int k = 0; k < 8; ++k) {
    float4 cv = Cr[l + 64 * k];
    double2 z0 = zr[2 * (l + 64 * k)];
    double2 z1 = zr[2 * (l + 64 * k) + 1];
    float4 f;
    f.x = (float)(4096.0 * fmin(wi * z0.x * fexp(-20.0 * (double)cv.x), 1.0));
    f.y = (float)(4096.0 * fmin(wi * z0.y * fexp(-20.0 * (double)cv.y), 1.0));
    f.z = (float)(4096.0 * fmin(wi * z1.x * fexp(-20.0 * (double)cv.z), 1.0));
    f.w = (float)(4096.0 * fmin(wi * z1.y * fexp(-20.0 * (double)cv.w), 1.0));
    ((float4*)orow)[l + 64 * k] = f;
  }
  float cr = (float)(4096.0 * fmin(wi * zpad, 1.0));
  float4 fc;
  fc.x = cr; fc.y = cr; fc.z = cr; fc.w = cr;
#pragma unroll
  for (int k = 0; k < 8; ++k) ((float4*)(orow + 2048))[l + 64 * k] = fc;
}

// Output rows 2048..4092 (all identical): j<2048 -> 4096*min(wpad*z_j,1),
// j>=2048 -> 4096*min(wpad*zpad,1). 256 blocks x 512 thr.
__global__ __launch_bounds__(512) void k_out_bot(char* base) {
  const double* z = (const double*)(base + OFF_Z);
  const double* scal = (const double*)(base + OFF_SCAL);
  float* out = (float*)base;
  __shared__ float s_val[2048];
  int tid = threadIdx.x, b = blockIdx.x;
  double wpad = scal[0], zpad = scal[1];
  {
    int j = tid * 4;
    double2 z0 = ((const double2*)(z + j))[0];
    double2 z1 = ((const double2*)(z + j))[1];
    s_val[j + 0] = (float)(4096.0 * fmin(wpad * z0.x, 1.0));
    s_val[j + 1] = (float)(4096.0 * fmin(wpad * z0.y, 1.0));
    s_val[j + 2] = (float)(4096.0 * fmin(wpad * z1.x, 1.0));
    s_val[j + 3] = (float)(4096.0 * fmin(wpad * z1.y, 1.0));
  }
  float cf = (float)(4096.0 * fmin(wpad * zpad, 1.0));
  __syncthreads();
  int wv = tid >> 6, l = tid & 63;
  int row = 2048 + b * 8 + wv;
  if (row <= 4092) {
    float4* orow = (float4*)(out + (size_t)row * 4096);
    float4 fc;
    fc.x = cf; fc.y = cf; fc.z = cf; fc.w = cf;
#pragma unroll
    for (int k = 0; k < 8; ++k) orow[l + 64 * k] = ((const float4*)s_val)[l + 64 * k];
#pragma unroll
    for (int k = 0; k < 8; ++k) orow[512 + l + 64 * k] = fc;
  }
}

// Output rows 4093..4095 (overwrites the w/z/scal stash; single block, staged).
__global__ __launch_bounds__(512) void k_out_tail(char* base) {
  const double* z = (const double*)(base + OFF_Z);
  const double* scal = (const double*)(base + OFF_SCAL);
  float* out = (float*)base;
  __shared__ float s_val[2048];
  int tid = threadIdx.x;
  double wpad = scal[0], zpad = scal[1];
  {
    int j = tid * 4;
    double2 z0 = ((const double2*)(z + j))[0];
    double2 z1 = ((const double2*)(z + j))[1];
    s_val[j + 0] = (float)(4096.0 * fmin(wpad * z0.x, 1.0));
    s_val[j + 1] = (float)(4096.0 * fmin(wpad * z0.y, 1.0));
    s_val[j + 2] = (float)(4096.0 * fmin(wpad * z1.x, 1.0));
    s_val[j + 3] = (float)(4096.0 * fmin(wpad * z1.y, 1.0));
  }
  float cf = (float)(4096.0 * fmin(wpad * zpad, 1.0));
  __syncthreads();  // all reads of z/scal complete before writes below
  float4 fc;
  fc.x = cf; fc.y = cf; fc.z = cf; fc.w = cf;
  for (int row = 4093; row <= 4095; ++row) {
    float4* orow = (float4*)(out + (size_t)row * 4096);
    for (int t = tid; t < 1024; t += 512)
      orow[t] = (t < 512) ? ((const float4*)s_val)[t] : fc;
  }
}

extern "C" void kernel_launch(void* const* d_in, const int* in_sizes, int n_in,
                              void* d_out, int out_size, void* d_ws, size_t ws_size,
                              hipStream_t stream) {
  (void)in_sizes; (void)n_in; (void)d_ws; (void)ws_size; (void)out_size;
  const float* C = (const float*)d_in[0];
  char* base = (char*)d_out;
  const float* K = (const float*)(base + OFF_K);
  const float* KT = (const float*)(base + OFF_KT);
  double* w = (double*)(base + OFF_W);
  double* z = (double*)(base + OFF_Z);
  double* scal = (double*)(base + OFF_SCAL);
  double* SwB = (double*)(base + OFF_SWB);
  double* SzB = (double*)(base + OFF_SZB);

  k_build<<<1024, 256, 0, stream>>>(C, base);
  for (int t = 0; t < 50; ++t) {
    // row update: w from z   (pad: wpad from sum(z))
    k_half<<<256, 512, 0, stream>>>(K, z, w, SzB, SwB, scal + 1, scal + 0);
    // col update: z from w   (pad: zpad from sum(w))
    k_half<<<256, 512, 0, stream>>>(KT, w, z, SwB, SzB, scal + 0, scal + 1);
  }
  k_out_top<<<256, 512, 0, stream>>>(C, base);
  k_out_bot<<<256, 512, 0, stream>>>(base);
  k_out_tail<<<1, 512, 0, stream>>>(base);
}